// Round 3
// baseline (2193.530 us; speedup 1.0000x reference)
//
#include <hip/hip_runtime.h>
#include <math.h>

#define NPTS 524288
#define TSZ  524288
#define TMASK (TSZ - 1)

__device__ __constant__ float NLf[16] = {
    16.f, 22.f, 30.f, 42.f, 58.f, 80.f, 110.f, 152.f,
    209.f, 288.f, 397.f, 547.f, 754.f, 1039.f, 1432.f, 1974.f
};

// ceil-selector bitmasks over vertex k (bit k set => use ceil on that axis)
#define CEILX 0xE2
#define CEILY 0xD4
#define CEILZ 0xB8

// ---------------- split kernel 1: hash gather, one (point, level) per thread ----
__global__ __launch_bounds__(256) void ngp_hash(
    const float* __restrict__ x, const float* __restrict__ tables,
    float2* __restrict__ feats_ws)
{
    const int i = blockIdx.x * 256 + threadIdx.x;   // point
    const int l = blockIdx.y;                        // level (varies slowest -> L2 locality)
    const float xu0 = x[3*i+0] / 3.0f + 0.5f;
    const float xu1 = x[3*i+1] / 3.0f + 0.5f;
    const float xu2 = x[3*i+2] / 3.0f + 0.5f;

    const float n = NLf[l];
    const float p0 = xu0 * n, p1 = xu1 * n, p2 = xu2 * n;
    const float f0 = floorf(p0), f1 = floorf(p1), f2 = floorf(p2);
    const float fr0 = p0 - f0, fr1 = p1 - f1, fr2 = p2 - f2;
    const int vf0 = (int)f0, vf1 = (int)f1, vf2 = (int)f2;
    const int vc0 = (int)ceilf(p0), vc1 = (int)ceilf(p1), vc2 = (int)ceilf(p2);
    const float2* tbl = (const float2*)(tables) + (size_t)l * TSZ;

    float a0 = 0.f, a1 = 0.f;
    #pragma unroll
    for (int k = 0; k < 8; ++k) {
        const unsigned vx = (unsigned)(((CEILX >> k) & 1) ? vc0 : vf0);
        const unsigned vy = (unsigned)(((CEILY >> k) & 1) ? vc1 : vf1);
        const unsigned vz = (unsigned)(((CEILZ >> k) & 1) ? vc2 : vf2);
        const unsigned h = (vx ^ (vy * 2654435761u) ^ (vz * 805459861u)) & TMASK;
        const float wx = (k & 1)        ? fr0 : 1.0f - fr0;
        const float wy = ((k >> 1) & 1) ? fr1 : 1.0f - fr1;
        const float wz = ((k >> 2) & 1) ? fr2 : 1.0f - fr2;
        const float wgt = wx * wy * wz;
        const float2 t = tbl[h];
        a0 = fmaf(wgt, t.x, a0);
        a1 = fmaf(wgt, t.y, a1);
    }
    feats_ws[(size_t)l * NPTS + i] = make_float2(a0, a1);
}

// ---------------- split kernel 2: MLPs ----------------
// __launch_bounds__(256, 2): 2 waves/EU -> VGPR cap 256. Without this the
// compiler targets 4 waves/EU (128 VGPR) and spills h1/z/z1 into AGPRs
// (v_accvgpr_read/write = VALU), blowing VALU issue up 17x (R2 post-mortem).
__global__ __launch_bounds__(256, 2) void ngp_mlp(
    const float* __restrict__ x, const float* __restrict__ d,
    const float2* __restrict__ feats_ws,
    const float* __restrict__ w1a, const float* __restrict__ b1a,
    const float* __restrict__ w1b, const float* __restrict__ b1b,
    const float* __restrict__ w2a, const float* __restrict__ b2a,
    const float* __restrict__ w2b, const float* __restrict__ b2b,
    const float* __restrict__ w2c, const float* __restrict__ b2c,
    float* __restrict__ out)
{
    const int i = blockIdx.x * 256 + threadIdx.x;

    const float xs0 = x[3*i+0] / 3.0f;
    const float xs1 = x[3*i+1] / 3.0f;
    const float xs2 = x[3*i+2] / 3.0f;
    const bool mask = (fabsf(xs0) < 0.5f) & (fabsf(xs1) < 0.5f) & (fabsf(xs2) < 0.5f);

    float feats[32];
    #pragma unroll
    for (int l = 0; l < 16; ++l) {
        const float2 t = feats_ws[(size_t)l * NPTS + i];
        feats[2*l] = t.x; feats[2*l+1] = t.y;
    }

    // ---- MLP1: [32] -> relu -> [64] -> [16] ----
    float h2v[16];
    {
        float h1[64];
        #pragma unroll
        for (int j = 0; j < 64; ++j) h1[j] = b1a[j];
        #pragma unroll
        for (int i2 = 0; i2 < 32; ++i2) {
            const float f = feats[i2];
            #pragma unroll
            for (int j = 0; j < 64; ++j) h1[j] = fmaf(f, w1a[i2*64 + j], h1[j]);
        }
        #pragma unroll
        for (int j = 0; j < 64; ++j) h1[j] = fmaxf(h1[j], 0.f);

        #pragma unroll
        for (int j = 0; j < 16; ++j) h2v[j] = b1b[j];
        #pragma unroll
        for (int i2 = 0; i2 < 64; ++i2) {
            const float f = h1[i2];
            #pragma unroll
            for (int j = 0; j < 16; ++j) h2v[j] = fmaf(f, w1b[i2*16 + j], h2v[j]);
        }
    }

    // ---- z = [h (16), posenc(d) (27)] ----
    const float d0 = d[3*i+0], d1 = d[3*i+1], d2 = d[3*i+2];
    float z[43];
    #pragma unroll
    for (int j = 0; j < 16; ++j) z[j] = h2v[j];
    z[16] = d0; z[17] = d1; z[18] = d2;
    #pragma unroll
    for (int e = 0; e < 4; ++e) {
        const float m = (float)(1 << e);
        z[19 + 6*e + 0] = sinf(m * d0);
        z[19 + 6*e + 1] = sinf(m * d1);
        z[19 + 6*e + 2] = sinf(m * d2);
        z[19 + 6*e + 3] = cosf(m * d0);
        z[19 + 6*e + 4] = cosf(m * d1);
        z[19 + 6*e + 5] = cosf(m * d2);
    }

    // ---- layer 2a: [43] -> relu[64] ----
    float z1[64];
    #pragma unroll
    for (int j = 0; j < 64; ++j) z1[j] = b2a[j];
    #pragma unroll
    for (int i2 = 0; i2 < 43; ++i2) {
        const float f = z[i2];
        #pragma unroll
        for (int j = 0; j < 64; ++j) z1[j] = fmaf(f, w2a[i2*64 + j], z1[j]);
    }
    #pragma unroll
    for (int j = 0; j < 64; ++j) z1[j] = fmaxf(z1[j], 0.f);

    // ---- layer 2b (relu) fused with 2c ----
    float ca = b2c[0], cb = b2c[1], cc = b2c[2];
    #pragma unroll
    for (int jc = 0; jc < 64; jc += 16) {
        float acc[16];
        #pragma unroll
        for (int jj = 0; jj < 16; ++jj) acc[jj] = b2b[jc + jj];
        #pragma unroll
        for (int i2 = 0; i2 < 64; ++i2) {
            const float f = z1[i2];
            #pragma unroll
            for (int jj = 0; jj < 16; ++jj)
                acc[jj] = fmaf(f, w2b[i2*64 + jc + jj], acc[jj]);
        }
        #pragma unroll
        for (int jj = 0; jj < 16; ++jj) {
            const float v = fmaxf(acc[jj], 0.f);
            ca = fmaf(v, w2c[(jc + jj)*3 + 0], ca);
            cb = fmaf(v, w2c[(jc + jj)*3 + 1], cb);
            cc = fmaf(v, w2c[(jc + jj)*3 + 2], cc);
        }
    }

    float r = 1.0f / (1.0f + expf(-ca));
    float g = 1.0f / (1.0f + expf(-cb));
    float b = 1.0f / (1.0f + expf(-cc));
    float sigma;
    if (mask) {
        sigma = expf(h2v[0]);
    } else {
        r = 0.f; g = 0.f; b = 0.f; sigma = 0.f;
    }
    out[3*i + 0] = r;
    out[3*i + 1] = g;
    out[3*i + 2] = b;
    out[3*NPTS + i] = sigma;
}

// ---------------- fallback: fused kernel (if ws too small) ----------
__global__ __launch_bounds__(256) void ngp_fused(
    const float* __restrict__ x, const float* __restrict__ d,
    const float* __restrict__ tables,
    const float* __restrict__ w1a, const float* __restrict__ b1a,
    const float* __restrict__ w1b, const float* __restrict__ b1b,
    const float* __restrict__ w2a, const float* __restrict__ b2a,
    const float* __restrict__ w2b, const float* __restrict__ b2b,
    const float* __restrict__ w2c, const float* __restrict__ b2c,
    float* __restrict__ out)
{
    const int i = blockIdx.x * 256 + threadIdx.x;
    if (i >= NPTS) return;
    const float xs0 = x[3*i+0] / 3.0f;
    const float xs1 = x[3*i+1] / 3.0f;
    const float xs2 = x[3*i+2] / 3.0f;
    const bool mask = (fabsf(xs0) < 0.5f) & (fabsf(xs1) < 0.5f) & (fabsf(xs2) < 0.5f);
    const float xu0 = xs0 + 0.5f, xu1 = xs1 + 0.5f, xu2 = xs2 + 0.5f;

    float feats[32];
    #pragma unroll
    for (int l = 0; l < 16; ++l) {
        const float n = NLf[l];
        const float p0 = xu0 * n, p1 = xu1 * n, p2 = xu2 * n;
        const float f0 = floorf(p0), f1 = floorf(p1), f2 = floorf(p2);
        const float fr0 = p0 - f0, fr1 = p1 - f1, fr2 = p2 - f2;
        const int vf0 = (int)f0, vf1 = (int)f1, vf2 = (int)f2;
        const int vc0 = (int)ceilf(p0), vc1 = (int)ceilf(p1), vc2 = (int)ceilf(p2);
        const float2* tbl = (const float2*)(tables + (size_t)l * (TSZ * 2));
        float a0 = 0.f, a1 = 0.f;
        #pragma unroll
        for (int k = 0; k < 8; ++k) {
            const unsigned vx = (unsigned)(((CEILX >> k) & 1) ? vc0 : vf0);
            const unsigned vy = (unsigned)(((CEILY >> k) & 1) ? vc1 : vf1);
            const unsigned vz = (unsigned)(((CEILZ >> k) & 1) ? vc2 : vf2);
            const unsigned h = (vx ^ (vy * 2654435761u) ^ (vz * 805459861u)) & TMASK;
            const float wx = (k & 1)        ? fr0 : 1.0f - fr0;
            const float wy = ((k >> 1) & 1) ? fr1 : 1.0f - fr1;
            const float wz = ((k >> 2) & 1) ? fr2 : 1.0f - fr2;
            const float wgt = wx * wy * wz;
            const float2 t = tbl[h];
            a0 = fmaf(wgt, t.x, a0);
            a1 = fmaf(wgt, t.y, a1);
        }
        feats[2*l] = a0; feats[2*l+1] = a1;
    }

    float h2v[16];
    {
        float h1[64];
        #pragma unroll
        for (int j = 0; j < 64; ++j) h1[j] = b1a[j];
        #pragma unroll
        for (int i2 = 0; i2 < 32; ++i2) {
            const float f = feats[i2];
            #pragma unroll
            for (int j = 0; j < 64; ++j) h1[j] = fmaf(f, w1a[i2*64 + j], h1[j]);
        }
        #pragma unroll
        for (int j = 0; j < 64; ++j) h1[j] = fmaxf(h1[j], 0.f);
        #pragma unroll
        for (int j = 0; j < 16; ++j) h2v[j] = b1b[j];
        #pragma unroll
        for (int i2 = 0; i2 < 64; ++i2) {
            const float f = h1[i2];
            #pragma unroll
            for (int j = 0; j < 16; ++j) h2v[j] = fmaf(f, w1b[i2*16 + j], h2v[j]);
        }
    }

    const float d0 = d[3*i+0], d1 = d[3*i+1], d2 = d[3*i+2];
    float z[43];
    #pragma unroll
    for (int j = 0; j < 16; ++j) z[j] = h2v[j];
    z[16] = d0; z[17] = d1; z[18] = d2;
    #pragma unroll
    for (int e = 0; e < 4; ++e) {
        const float m = (float)(1 << e);
        z[19 + 6*e + 0] = sinf(m * d0);
        z[19 + 6*e + 1] = sinf(m * d1);
        z[19 + 6*e + 2] = sinf(m * d2);
        z[19 + 6*e + 3] = cosf(m * d0);
        z[19 + 6*e + 4] = cosf(m * d1);
        z[19 + 6*e + 5] = cosf(m * d2);
    }

    float z1[64];
    #pragma unroll
    for (int j = 0; j < 64; ++j) z1[j] = b2a[j];
    #pragma unroll
    for (int i2 = 0; i2 < 43; ++i2) {
        const float f = z[i2];
        #pragma unroll
        for (int j = 0; j < 64; ++j) z1[j] = fmaf(f, w2a[i2*64 + j], z1[j]);
    }
    #pragma unroll
    for (int j = 0; j < 64; ++j) z1[j] = fmaxf(z1[j], 0.f);

    float ca = b2c[0], cb = b2c[1], cc = b2c[2];
    #pragma unroll
    for (int jc = 0; jc < 64; jc += 16) {
        float acc[16];
        #pragma unroll
        for (int jj = 0; jj < 16; ++jj) acc[jj] = b2b[jc + jj];
        #pragma unroll
        for (int i2 = 0; i2 < 64; ++i2) {
            const float f = z1[i2];
            #pragma unroll
            for (int jj = 0; jj < 16; ++jj)
                acc[jj] = fmaf(f, w2b[i2*64 + jc + jj], acc[jj]);
        }
        #pragma unroll
        for (int jj = 0; jj < 16; ++jj) {
            const float v = fmaxf(acc[jj], 0.f);
            ca = fmaf(v, w2c[(jc + jj)*3 + 0], ca);
            cb = fmaf(v, w2c[(jc + jj)*3 + 1], cb);
            cc = fmaf(v, w2c[(jc + jj)*3 + 2], cc);
        }
    }

    float r = 1.0f / (1.0f + expf(-ca));
    float g = 1.0f / (1.0f + expf(-cb));
    float b = 1.0f / (1.0f + expf(-cc));
    float sigma;
    if (mask) { sigma = expf(h2v[0]); }
    else { r = 0.f; g = 0.f; b = 0.f; sigma = 0.f; }
    out[3*i + 0] = r;
    out[3*i + 1] = g;
    out[3*i + 2] = b;
    out[3*NPTS + i] = sigma;
}

extern "C" void kernel_launch(void* const* d_in, const int* in_sizes, int n_in,
                              void* d_out, int out_size, void* d_ws, size_t ws_size,
                              hipStream_t stream) {
    const float* x      = (const float*)d_in[0];
    const float* d      = (const float*)d_in[1];
    const float* tables = (const float*)d_in[2];
    const float* w1a    = (const float*)d_in[3];
    const float* b1a    = (const float*)d_in[4];
    const float* w1b    = (const float*)d_in[5];
    const float* b1b    = (const float*)d_in[6];
    const float* w2a    = (const float*)d_in[7];
    const float* b2a    = (const float*)d_in[8];
    const float* w2b    = (const float*)d_in[9];
    const float* b2b    = (const float*)d_in[10];
    const float* w2c    = (const float*)d_in[11];
    const float* b2c    = (const float*)d_in[12];
    float* out = (float*)d_out;

    const size_t need = (size_t)NPTS * 16 * sizeof(float2);  // 64 MiB
    if (ws_size >= need) {
        float2* feats_ws = (float2*)d_ws;
        dim3 gh(NPTS / 256, 16), bh(256);
        hipLaunchKernelGGL(ngp_hash, gh, bh, 0, stream, x, tables, feats_ws);
        dim3 gm(NPTS / 256), bm(256);
        hipLaunchKernelGGL(ngp_mlp, gm, bm, 0, stream,
                           x, d, feats_ws, w1a, b1a, w1b, b1b,
                           w2a, b2a, w2b, b2b, w2c, b2c, out);
    } else {
        dim3 grid(NPTS / 256), block(256);
        hipLaunchKernelGGL(ngp_fused, grid, block, 0, stream,
                           x, d, tables, w1a, b1a, w1b, b1b,
                           w2a, b2a, w2b, b2b, w2c, b2c, out);
    }
}

// Round 4
// 638.091 us; speedup vs baseline: 3.4376x; 3.4376x over previous
//
#include <hip/hip_runtime.h>
#include <math.h>

#define NPTS 524288
#define TSZ  524288
#define TMASK (TSZ - 1)

__device__ __constant__ float NLf[16] = {
    16.f, 22.f, 30.f, 42.f, 58.f, 80.f, 110.f, 152.f,
    209.f, 288.f, 397.f, 547.f, 754.f, 1039.f, 1432.f, 1974.f
};

// ceil-selector bitmasks over vertex k (bit k set => use ceil on that axis)
#define CEILX 0xE2
#define CEILY 0xD4
#define CEILZ 0xB8

// ---------------- kernel 1: hash gather, one (point, level) per thread ------
__global__ __launch_bounds__(256) void ngp_hash(
    const float* __restrict__ x, const float* __restrict__ tables,
    float2* __restrict__ feats_ws)
{
    const int i = blockIdx.x * 256 + threadIdx.x;   // point
    const int l = blockIdx.y;                        // level (slowest -> L2 locality)
    const float xu0 = x[3*i+0] / 3.0f + 0.5f;
    const float xu1 = x[3*i+1] / 3.0f + 0.5f;
    const float xu2 = x[3*i+2] / 3.0f + 0.5f;

    const float n = NLf[l];
    const float p0 = xu0 * n, p1 = xu1 * n, p2 = xu2 * n;
    const float f0 = floorf(p0), f1 = floorf(p1), f2 = floorf(p2);
    const float fr0 = p0 - f0, fr1 = p1 - f1, fr2 = p2 - f2;
    const int vf0 = (int)f0, vf1 = (int)f1, vf2 = (int)f2;
    const int vc0 = (int)ceilf(p0), vc1 = (int)ceilf(p1), vc2 = (int)ceilf(p2);
    const float2* tbl = (const float2*)(tables) + (size_t)l * TSZ;

    float a0 = 0.f, a1 = 0.f;
    #pragma unroll
    for (int k = 0; k < 8; ++k) {
        const unsigned vx = (unsigned)(((CEILX >> k) & 1) ? vc0 : vf0);
        const unsigned vy = (unsigned)(((CEILY >> k) & 1) ? vc1 : vf1);
        const unsigned vz = (unsigned)(((CEILZ >> k) & 1) ? vc2 : vf2);
        const unsigned h = (vx ^ (vy * 2654435761u) ^ (vz * 805459861u)) & TMASK;
        const float wx = (k & 1)        ? fr0 : 1.0f - fr0;
        const float wy = ((k >> 1) & 1) ? fr1 : 1.0f - fr1;
        const float wz = ((k >> 2) & 1) ? fr2 : 1.0f - fr2;
        const float wgt = wx * wy * wz;
        const float2 t = tbl[h];
        a0 = fmaf(wgt, t.x, a0);
        a1 = fmaf(wgt, t.y, a1);
    }
    feats_ws[(size_t)l * NPTS + i] = make_float2(a0, a1);
}

// ---------------- kernel 2: MLPs, restructured for low register pressure ----
// R2/R3 post-mortem: with the naive structure (h1[64] + z[43] + z1[64] live)
// the allocator spills (AGPR at 128-cap, scratch with waves_per_eu=2 hint).
// Restructure so peak live ~90 floats: h1 computed in 16-chunks folded into
// h2v immediately; z[] never materialized (posenc scalars FMA'd straight into
// the z1[64] accumulators). No waves-per-EU hint (it made things worse).
__global__ __launch_bounds__(256) void ngp_mlp(
    const float* __restrict__ x, const float* __restrict__ d,
    const float2* __restrict__ feats_ws,
    const float* __restrict__ w1a, const float* __restrict__ b1a,
    const float* __restrict__ w1b, const float* __restrict__ b1b,
    const float* __restrict__ w2a, const float* __restrict__ b2a,
    const float* __restrict__ w2b, const float* __restrict__ b2b,
    const float* __restrict__ w2c, const float* __restrict__ b2c,
    float* __restrict__ out)
{
    const int i = blockIdx.x * 256 + threadIdx.x;

    const float xs0 = x[3*i+0] / 3.0f;
    const float xs1 = x[3*i+1] / 3.0f;
    const float xs2 = x[3*i+2] / 3.0f;
    const bool mask = (fabsf(xs0) < 0.5f) & (fabsf(xs1) < 0.5f) & (fabsf(xs2) < 0.5f);

    float feats[32];
    #pragma unroll
    for (int l = 0; l < 16; ++l) {
        const float2 t = feats_ws[(size_t)l * NPTS + i];
        feats[2*l] = t.x; feats[2*l+1] = t.y;
    }

    // ---- MLP1: h2v[16] = relu(feats@w1a+b1a)@w1b + b1b, h1 in 16-chunks ----
    float h2v[16];
    #pragma unroll
    for (int j = 0; j < 16; ++j) h2v[j] = b1b[j];
    #pragma unroll
    for (int c = 0; c < 4; ++c) {
        float h1c[16];
        #pragma unroll
        for (int jj = 0; jj < 16; ++jj) h1c[jj] = b1a[16*c + jj];
        #pragma unroll
        for (int i2 = 0; i2 < 32; ++i2) {
            const float f = feats[i2];
            #pragma unroll
            for (int jj = 0; jj < 16; ++jj)
                h1c[jj] = fmaf(f, w1a[i2*64 + 16*c + jj], h1c[jj]);
        }
        #pragma unroll
        for (int jj = 0; jj < 16; ++jj) {
            const float f = fmaxf(h1c[jj], 0.f);
            #pragma unroll
            for (int t = 0; t < 16; ++t)
                h2v[t] = fmaf(f, w1b[(16*c + jj)*16 + t], h2v[t]);
        }
    }

    // ---- layer 2a accumulators; posenc scalars folded in on the fly ----
    float z1[64];
    #pragma unroll
    for (int j = 0; j < 64; ++j) z1[j] = b2a[j];
    #pragma unroll
    for (int i2 = 0; i2 < 16; ++i2) {
        const float f = h2v[i2];
        #pragma unroll
        for (int j = 0; j < 64; ++j) z1[j] = fmaf(f, w2a[i2*64 + j], z1[j]);
    }
    const float d0 = d[3*i+0], d1 = d[3*i+1], d2 = d[3*i+2];
    {
        const float* r = w2a + 16*64;
        #pragma unroll
        for (int j = 0; j < 64; ++j) z1[j] = fmaf(d0, r[j], z1[j]);
        r = w2a + 17*64;
        #pragma unroll
        for (int j = 0; j < 64; ++j) z1[j] = fmaf(d1, r[j], z1[j]);
        r = w2a + 18*64;
        #pragma unroll
        for (int j = 0; j < 64; ++j) z1[j] = fmaf(d2, r[j], z1[j]);
    }
    #pragma unroll
    for (int e = 0; e < 4; ++e) {
        const float m = (float)(1 << e);
        const float dv[3] = {d0, d1, d2};
        #pragma unroll
        for (int a = 0; a < 3; ++a) {
            const float sv = __sinf(m * dv[a]);
            const float* rs = w2a + (19 + 6*e + a)*64;
            #pragma unroll
            for (int j = 0; j < 64; ++j) z1[j] = fmaf(sv, rs[j], z1[j]);
        }
        #pragma unroll
        for (int a = 0; a < 3; ++a) {
            const float cv = __cosf(m * dv[a]);
            const float* rc = w2a + (19 + 6*e + 3 + a)*64;
            #pragma unroll
            for (int j = 0; j < 64; ++j) z1[j] = fmaf(cv, rc[j], z1[j]);
        }
    }
    #pragma unroll
    for (int j = 0; j < 64; ++j) z1[j] = fmaxf(z1[j], 0.f);

    // ---- layer 2b (relu) fused with 2c, 16-output chunks ----
    float ca = b2c[0], cb = b2c[1], cc = b2c[2];
    #pragma unroll
    for (int jc = 0; jc < 64; jc += 16) {
        float acc[16];
        #pragma unroll
        for (int jj = 0; jj < 16; ++jj) acc[jj] = b2b[jc + jj];
        #pragma unroll
        for (int i2 = 0; i2 < 64; ++i2) {
            const float f = z1[i2];
            #pragma unroll
            for (int jj = 0; jj < 16; ++jj)
                acc[jj] = fmaf(f, w2b[i2*64 + jc + jj], acc[jj]);
        }
        #pragma unroll
        for (int jj = 0; jj < 16; ++jj) {
            const float v = fmaxf(acc[jj], 0.f);
            ca = fmaf(v, w2c[(jc + jj)*3 + 0], ca);
            cb = fmaf(v, w2c[(jc + jj)*3 + 1], cb);
            cc = fmaf(v, w2c[(jc + jj)*3 + 2], cc);
        }
    }

    float r = 1.0f / (1.0f + __expf(-ca));
    float g = 1.0f / (1.0f + __expf(-cb));
    float b = 1.0f / (1.0f + __expf(-cc));
    float sigma;
    if (mask) {
        sigma = __expf(h2v[0]);
    } else {
        r = 0.f; g = 0.f; b = 0.f; sigma = 0.f;
    }
    out[3*i + 0] = r;
    out[3*i + 1] = g;
    out[3*i + 2] = b;
    out[3*NPTS + i] = sigma;
}

// ---------------- fallback: fused kernel (if ws too small) ----------
__global__ __launch_bounds__(256) void ngp_fused(
    const float* __restrict__ x, const float* __restrict__ d,
    const float* __restrict__ tables,
    const float* __restrict__ w1a, const float* __restrict__ b1a,
    const float* __restrict__ w1b, const float* __restrict__ b1b,
    const float* __restrict__ w2a, const float* __restrict__ b2a,
    const float* __restrict__ w2b, const float* __restrict__ b2b,
    const float* __restrict__ w2c, const float* __restrict__ b2c,
    float* __restrict__ out)
{
    const int i = blockIdx.x * 256 + threadIdx.x;
    if (i >= NPTS) return;
    const float xs0 = x[3*i+0] / 3.0f;
    const float xs1 = x[3*i+1] / 3.0f;
    const float xs2 = x[3*i+2] / 3.0f;
    const bool mask = (fabsf(xs0) < 0.5f) & (fabsf(xs1) < 0.5f) & (fabsf(xs2) < 0.5f);
    const float xu0 = xs0 + 0.5f, xu1 = xs1 + 0.5f, xu2 = xs2 + 0.5f;

    float feats[32];
    #pragma unroll
    for (int l = 0; l < 16; ++l) {
        const float n = NLf[l];
        const float p0 = xu0 * n, p1 = xu1 * n, p2 = xu2 * n;
        const float f0 = floorf(p0), f1 = floorf(p1), f2 = floorf(p2);
        const float fr0 = p0 - f0, fr1 = p1 - f1, fr2 = p2 - f2;
        const int vf0 = (int)f0, vf1 = (int)f1, vf2 = (int)f2;
        const int vc0 = (int)ceilf(p0), vc1 = (int)ceilf(p1), vc2 = (int)ceilf(p2);
        const float2* tbl = (const float2*)(tables + (size_t)l * (TSZ * 2));
        float a0 = 0.f, a1 = 0.f;
        #pragma unroll
        for (int k = 0; k < 8; ++k) {
            const unsigned vx = (unsigned)(((CEILX >> k) & 1) ? vc0 : vf0);
            const unsigned vy = (unsigned)(((CEILY >> k) & 1) ? vc1 : vf1);
            const unsigned vz = (unsigned)(((CEILZ >> k) & 1) ? vc2 : vf2);
            const unsigned h = (vx ^ (vy * 2654435761u) ^ (vz * 805459861u)) & TMASK;
            const float wx = (k & 1)        ? fr0 : 1.0f - fr0;
            const float wy = ((k >> 1) & 1) ? fr1 : 1.0f - fr1;
            const float wz = ((k >> 2) & 1) ? fr2 : 1.0f - fr2;
            const float wgt = wx * wy * wz;
            const float2 t = tbl[h];
            a0 = fmaf(wgt, t.x, a0);
            a1 = fmaf(wgt, t.y, a1);
        }
        feats[2*l] = a0; feats[2*l+1] = a1;
    }

    float h2v[16];
    {
        float h1[64];
        #pragma unroll
        for (int j = 0; j < 64; ++j) h1[j] = b1a[j];
        #pragma unroll
        for (int i2 = 0; i2 < 32; ++i2) {
            const float f = feats[i2];
            #pragma unroll
            for (int j = 0; j < 64; ++j) h1[j] = fmaf(f, w1a[i2*64 + j], h1[j]);
        }
        #pragma unroll
        for (int j = 0; j < 64; ++j) h1[j] = fmaxf(h1[j], 0.f);
        #pragma unroll
        for (int j = 0; j < 16; ++j) h2v[j] = b1b[j];
        #pragma unroll
        for (int i2 = 0; i2 < 64; ++i2) {
            const float f = h1[i2];
            #pragma unroll
            for (int j = 0; j < 16; ++j) h2v[j] = fmaf(f, w1b[i2*16 + j], h2v[j]);
        }
    }

    const float d0 = d[3*i+0], d1 = d[3*i+1], d2 = d[3*i+2];
    float z[43];
    #pragma unroll
    for (int j = 0; j < 16; ++j) z[j] = h2v[j];
    z[16] = d0; z[17] = d1; z[18] = d2;
    #pragma unroll
    for (int e = 0; e < 4; ++e) {
        const float m = (float)(1 << e);
        z[19 + 6*e + 0] = sinf(m * d0);
        z[19 + 6*e + 1] = sinf(m * d1);
        z[19 + 6*e + 2] = sinf(m * d2);
        z[19 + 6*e + 3] = cosf(m * d0);
        z[19 + 6*e + 4] = cosf(m * d1);
        z[19 + 6*e + 5] = cosf(m * d2);
    }

    float z1[64];
    #pragma unroll
    for (int j = 0; j < 64; ++j) z1[j] = b2a[j];
    #pragma unroll
    for (int i2 = 0; i2 < 43; ++i2) {
        const float f = z[i2];
        #pragma unroll
        for (int j = 0; j < 64; ++j) z1[j] = fmaf(f, w2a[i2*64 + j], z1[j]);
    }
    #pragma unroll
    for (int j = 0; j < 64; ++j) z1[j] = fmaxf(z1[j], 0.f);

    float ca = b2c[0], cb = b2c[1], cc = b2c[2];
    #pragma unroll
    for (int jc = 0; jc < 64; jc += 16) {
        float acc[16];
        #pragma unroll
        for (int jj = 0; jj < 16; ++jj) acc[jj] = b2b[jc + jj];
        #pragma unroll
        for (int i2 = 0; i2 < 64; ++i2) {
            const float f = z1[i2];
            #pragma unroll
            for (int jj = 0; jj < 16; ++jj)
                acc[jj] = fmaf(f, w2b[i2*64 + jc + jj], acc[jj]);
        }
        #pragma unroll
        for (int jj = 0; jj < 16; ++jj) {
            const float v = fmaxf(acc[jj], 0.f);
            ca = fmaf(v, w2c[(jc + jj)*3 + 0], ca);
            cb = fmaf(v, w2c[(jc + jj)*3 + 1], cb);
            cc = fmaf(v, w2c[(jc + jj)*3 + 2], cc);
        }
    }

    float r = 1.0f / (1.0f + expf(-ca));
    float g = 1.0f / (1.0f + expf(-cb));
    float b = 1.0f / (1.0f + expf(-cc));
    float sigma;
    if (mask) { sigma = expf(h2v[0]); }
    else { r = 0.f; g = 0.f; b = 0.f; sigma = 0.f; }
    out[3*i + 0] = r;
    out[3*i + 1] = g;
    out[3*i + 2] = b;
    out[3*NPTS + i] = sigma;
}

extern "C" void kernel_launch(void* const* d_in, const int* in_sizes, int n_in,
                              void* d_out, int out_size, void* d_ws, size_t ws_size,
                              hipStream_t stream) {
    const float* x      = (const float*)d_in[0];
    const float* d      = (const float*)d_in[1];
    const float* tables = (const float*)d_in[2];
    const float* w1a    = (const float*)d_in[3];
    const float* b1a    = (const float*)d_in[4];
    const float* w1b    = (const float*)d_in[5];
    const float* b1b    = (const float*)d_in[6];
    const float* w2a    = (const float*)d_in[7];
    const float* b2a    = (const float*)d_in[8];
    const float* w2b    = (const float*)d_in[9];
    const float* b2b    = (const float*)d_in[10];
    const float* w2c    = (const float*)d_in[11];
    const float* b2c    = (const float*)d_in[12];
    float* out = (float*)d_out;

    const size_t need = (size_t)NPTS * 16 * sizeof(float2);  // 64 MiB
    if (ws_size >= need) {
        float2* feats_ws = (float2*)d_ws;
        dim3 gh(NPTS / 256, 16), bh(256);
        hipLaunchKernelGGL(ngp_hash, gh, bh, 0, stream, x, tables, feats_ws);
        dim3 gm(NPTS / 256), bm(256);
        hipLaunchKernelGGL(ngp_mlp, gm, bm, 0, stream,
                           x, d, feats_ws, w1a, b1a, w1b, b1b,
                           w2a, b2a, w2b, b2b, w2c, b2c, out);
    } else {
        dim3 grid(NPTS / 256), block(256);
        hipLaunchKernelGGL(ngp_fused, grid, block, 0, stream,
                           x, d, tables, w1a, b1a, w1b, b1b,
                           w2a, b2a, w2b, b2b, w2c, b2c, out);
    }
}

// Round 5
// 436.257 us; speedup vs baseline: 5.0281x; 1.4626x over previous
//
#include <hip/hip_runtime.h>
#include <math.h>

#define NPTS 524288
#define HALF (NPTS / 2)
#define TSZ  524288
#define TMASK (TSZ - 1)

typedef __attribute__((ext_vector_type(8))) short v8s;   // 8 x bf16 (4 VGPR)
typedef __attribute__((ext_vector_type(4))) float v4f;   // MFMA C/D frag

#define MFMA16(a, b, c) __builtin_amdgcn_mfma_f32_16x16x32_bf16(a, b, c, 0, 0, 0)

__device__ __constant__ float NLf[16] = {
    16.f, 22.f, 30.f, 42.f, 58.f, 80.f, 110.f, 152.f,
    209.f, 288.f, 397.f, 547.f, 754.f, 1039.f, 1432.f, 1974.f
};

#define CEILX 0xE2
#define CEILY 0xD4
#define CEILZ 0xB8

__device__ __forceinline__ short bf16r(float v) {  // f32 -> bf16 RNE
    unsigned b = __float_as_uint(v);
    b += 0x7FFFu + ((b >> 16) & 1u);
    return (short)(b >> 16);
}

// ---------------- kernel 1: hash gather, 2 points per thread (ILP) ----------
__global__ __launch_bounds__(256) void ngp_hash2(
    const float* __restrict__ x, const float* __restrict__ tables,
    float2* __restrict__ feats_ws)
{
    const int i = blockIdx.x * 256 + threadIdx.x;    // [0, HALF)
    const int l = blockIdx.y;                        // level (slowest -> L2 locality)
    const float n = NLf[l];
    const float2* tbl = (const float2*)(tables) + (size_t)l * TSZ;

    #pragma unroll
    for (int pp = 0; pp < 2; ++pp) {
        const int p = i + pp * HALF;
        const float xu0 = x[3*p+0] / 3.0f + 0.5f;
        const float xu1 = x[3*p+1] / 3.0f + 0.5f;
        const float xu2 = x[3*p+2] / 3.0f + 0.5f;
        const float p0 = xu0 * n, p1 = xu1 * n, p2 = xu2 * n;
        const float f0 = floorf(p0), f1 = floorf(p1), f2 = floorf(p2);
        const float fr0 = p0 - f0, fr1 = p1 - f1, fr2 = p2 - f2;
        const int vf0 = (int)f0, vf1 = (int)f1, vf2 = (int)f2;
        const int vc0 = (int)ceilf(p0), vc1 = (int)ceilf(p1), vc2 = (int)ceilf(p2);
        float a0 = 0.f, a1 = 0.f;
        #pragma unroll
        for (int k = 0; k < 8; ++k) {
            const unsigned vx = (unsigned)(((CEILX >> k) & 1) ? vc0 : vf0);
            const unsigned vy = (unsigned)(((CEILY >> k) & 1) ? vc1 : vf1);
            const unsigned vz = (unsigned)(((CEILZ >> k) & 1) ? vc2 : vf2);
            const unsigned h = (vx ^ (vy * 2654435761u) ^ (vz * 805459861u)) & TMASK;
            const float wx = (k & 1)        ? fr0 : 1.0f - fr0;
            const float wy = ((k >> 1) & 1) ? fr1 : 1.0f - fr1;
            const float wz = ((k >> 2) & 1) ? fr2 : 1.0f - fr2;
            const float wgt = wx * wy * wz;
            const float2 t = tbl[h];
            a0 = fmaf(wgt, t.x, a0);
            a1 = fmaf(wgt, t.y, a1);
        }
        feats_ws[(size_t)l * NPTS + p] = make_float2(a0, a1);
    }
}

// ---------------- kernel 2: MFMA MLP --------------------------------------
// Per block: 256 thr = 4 waves; weights staged once to LDS as bf16 transposed
// [n][k] (pitch 16B-aligned). Each wave owns a 16-row LDS z-buffer and runs
// 4 tiles of 16 points: feats->L1a->L1b->(posenc fill)->L2a->L2b->L2c, all
// matmuls via mfma_f32_16x16x32_bf16.
// Layouts (m89/m120 verified): A: row=lane&15, k=quad*8+j; B: col=lane&15,
// k=quad*8+j; C/D: col=lane&15, row=quad*4+reg.
#define PZ 72   // z-buffer pitch in shorts (144 B, 16B-aligned)

__global__ __launch_bounds__(256) void ngp_mlp_mfma(
    const float* __restrict__ x, const float* __restrict__ d,
    const float2* __restrict__ feats_ws,
    const float* __restrict__ w1a, const float* __restrict__ b1a,
    const float* __restrict__ w1b, const float* __restrict__ b1b,
    const float* __restrict__ w2a, const float* __restrict__ b2a,
    const float* __restrict__ w2b, const float* __restrict__ b2b,
    const float* __restrict__ w2c, const float* __restrict__ b2c,
    float* __restrict__ out)
{
    __shared__ short sW1a[64 * 40];   // [n=64][k=32], pitch 40
    __shared__ short sW1b[16 * 72];   // [n=16][k=64], pitch 72
    __shared__ short sW2a[64 * 72];   // [n=64][k=64(43 real)], pitch 72
    __shared__ short sW2b[64 * 72];   // [n=64][k=64], pitch 72
    __shared__ short sW2c[16 * 72];   // [n=16(3 real)][k=64], pitch 72
    __shared__ short sZ[4 * 16 * PZ]; // per-wave 16-row z-buffer
    __shared__ float sMask[64];       // per-wave 16 masks

    const int tid = threadIdx.x;

    // ---- stage weights (bf16, transposed) ----
    for (int idx = tid; idx < 32 * 64; idx += 256) {
        const int k = idx >> 6, n2 = idx & 63;
        sW1a[n2 * 40 + k] = bf16r(w1a[k * 64 + n2]);
    }
    for (int idx = tid; idx < 64 * 16; idx += 256) {
        const int k = idx >> 4, n2 = idx & 15;
        sW1b[n2 * 72 + k] = bf16r(w1b[k * 16 + n2]);
    }
    for (int idx = tid; idx < 64 * 64; idx += 256) {
        const int k = idx >> 6, n2 = idx & 63;
        sW2a[n2 * 72 + k] = bf16r(k < 43 ? w2a[k * 64 + n2] : 0.f);
    }
    for (int idx = tid; idx < 64 * 64; idx += 256) {
        const int k = idx >> 6, n2 = idx & 63;
        sW2b[n2 * 72 + k] = bf16r(w2b[k * 64 + n2]);
    }
    for (int idx = tid; idx < 64 * 16; idx += 256) {
        const int k = idx >> 4, n2 = idx & 15;
        sW2c[n2 * 72 + k] = bf16r(n2 < 3 ? w2c[k * 3 + n2] : 0.f);
    }
    __syncthreads();

    const int wave = tid >> 6, lane = tid & 63;
    const int m = lane & 15, q = lane >> 4;
    short* zb = &sZ[wave * 16 * PZ];

    // hoisted per-lane biases
    float bb1a[4], bb2a[4], bb2b[4];
    #pragma unroll
    for (int ct = 0; ct < 4; ++ct) {
        bb1a[ct] = b1a[ct * 16 + m];
        bb2a[ct] = b2a[ct * 16 + m];
        bb2b[ct] = b2b[ct * 16 + m];
    }
    const float bb1b = b1b[m];
    const float bb2c = (m < 3) ? b2c[m] : 0.f;

    for (int tl = 0; tl < 4; ++tl) {
        const int p0 = ((blockIdx.x * 4 + wave) * 4 + tl) * 16;

        // ---- stage feats (bf16) into zb[pt][k0..31]; mask into sMask ----
        #pragma unroll
        for (int it = 0; it < 4; ++it) {
            const int l = it * 4 + q;
            const float2 f = feats_ws[(size_t)l * NPTS + p0 + m];
            const unsigned pk = (unsigned)(unsigned short)bf16r(f.x)
                              | ((unsigned)(unsigned short)bf16r(f.y) << 16);
            *(unsigned*)(zb + m * PZ + 2 * l) = pk;
        }
        if (lane < 16) {
            const int p = p0 + lane;
            const float xs0 = x[3*p+0] / 3.0f;
            const float xs1 = x[3*p+1] / 3.0f;
            const float xs2 = x[3*p+2] / 3.0f;
            sMask[wave * 16 + lane] =
                ((fabsf(xs0) < 0.5f) && (fabsf(xs1) < 0.5f) && (fabsf(xs2) < 0.5f)) ? 1.f : 0.f;
        }

        // ---- layer 1a: feats[16x32] @ w1a[32x64] -> relu -> h1 (bf16 in zb) ----
        {
            const v8s a0 = *(const v8s*)(zb + m * PZ + q * 8);
            #pragma unroll
            for (int ct = 0; ct < 4; ++ct) {
                const float bv = bb1a[ct];
                v4f acc = {bv, bv, bv, bv};
                const v8s b = *(const v8s*)(sW1a + (ct * 16 + m) * 40 + q * 8);
                acc = MFMA16(a0, b, acc);
                #pragma unroll
                for (int r = 0; r < 4; ++r)
                    zb[(q * 4 + r) * PZ + ct * 16 + m] = bf16r(fmaxf(acc[r], 0.f));
            }
        }

        // ---- layer 1b: h1[16x64] @ w1b[64x16] -> h (NO relu) ----
        v4f hacc;
        {
            const v8s a10 = *(const v8s*)(zb + m * PZ + q * 8);
            const v8s a11 = *(const v8s*)(zb + m * PZ + 32 + q * 8);
            hacc = (v4f){bb1b, bb1b, bb1b, bb1b};
            hacc = MFMA16(a10, *(const v8s*)(sW1b + m * 72 + q * 8), hacc);
            hacc = MFMA16(a11, *(const v8s*)(sW1b + m * 72 + 32 + q * 8), hacc);
            // write h into z[k=0..15] (no relu)
            #pragma unroll
            for (int r = 0; r < 4; ++r)
                zb[(q * 4 + r) * PZ + m] = bf16r(hacc[r]);
        }

        // ---- posenc fill: z[k=16..42], zeros k=43..63 ----
        {
            const int p = p0 + m;
            const float dd0 = d[3*p+0], dd1 = d[3*p+1], dd2 = d[3*p+2];
            v8s pk;
            #pragma unroll
            for (int j = 0; j < 8; ++j) {
                const int k = 16 + q * 8 + j;
                float v;
                if (k < 19) {
                    v = (k == 16) ? dd0 : ((k == 17) ? dd1 : dd2);
                } else if (k < 43) {
                    const int idx = k - 19;
                    const int e = idx / 6, w = idx - 6 * e;
                    const float base = (w == 0 || w == 3) ? dd0 : ((w == 1 || w == 4) ? dd1 : dd2);
                    const float s = (float)(1 << e) * base;
                    v = (w < 3) ? __sinf(s) : __cosf(s);
                } else {
                    v = 0.f;
                }
                pk[j] = bf16r(v);
            }
            *(v8s*)(zb + m * PZ + 16 + q * 8) = pk;                       // k=16+8q..23+8q
            *(unsigned long long*)(zb + m * PZ + 48 + q * 4) = 0ull;      // k=48+4q..51+4q
        }

        // ---- layer 2a: z[16x64(43)] @ w2a -> relu -> z1 ----
        {
            const v8s a20 = *(const v8s*)(zb + m * PZ + q * 8);
            const v8s a21 = *(const v8s*)(zb + m * PZ + 32 + q * 8);
            #pragma unroll
            for (int ct = 0; ct < 4; ++ct) {
                const float bv = bb2a[ct];
                v4f acc = {bv, bv, bv, bv};
                acc = MFMA16(a20, *(const v8s*)(sW2a + (ct * 16 + m) * 72 + q * 8), acc);
                acc = MFMA16(a21, *(const v8s*)(sW2a + (ct * 16 + m) * 72 + 32 + q * 8), acc);
                #pragma unroll
                for (int r = 0; r < 4; ++r)
                    zb[(q * 4 + r) * PZ + ct * 16 + m] = bf16r(fmaxf(acc[r], 0.f));
            }
        }

        // ---- layer 2b: z1[16x64] @ w2b -> relu -> z2 ----
        {
            const v8s a20 = *(const v8s*)(zb + m * PZ + q * 8);
            const v8s a21 = *(const v8s*)(zb + m * PZ + 32 + q * 8);
            #pragma unroll
            for (int ct = 0; ct < 4; ++ct) {
                const float bv = bb2b[ct];
                v4f acc = {bv, bv, bv, bv};
                acc = MFMA16(a20, *(const v8s*)(sW2b + (ct * 16 + m) * 72 + q * 8), acc);
                acc = MFMA16(a21, *(const v8s*)(sW2b + (ct * 16 + m) * 72 + 32 + q * 8), acc);
                #pragma unroll
                for (int r = 0; r < 4; ++r)
                    zb[(q * 4 + r) * PZ + ct * 16 + m] = bf16r(fmaxf(acc[r], 0.f));
            }
        }

        // ---- layer 2c: z2[16x64] @ w2c[64x3] -> sigmoid -> color; sigma ----
        {
            const v8s a30 = *(const v8s*)(zb + m * PZ + q * 8);
            const v8s a31 = *(const v8s*)(zb + m * PZ + 32 + q * 8);
            v4f cacc = {bb2c, bb2c, bb2c, bb2c};
            cacc = MFMA16(a30, *(const v8s*)(sW2c + m * 72 + q * 8), cacc);
            cacc = MFMA16(a31, *(const v8s*)(sW2c + m * 72 + 32 + q * 8), cacc);

            float mk[4];
            #pragma unroll
            for (int r = 0; r < 4; ++r) mk[r] = sMask[wave * 16 + q * 4 + r];

            if (m < 3) {
                #pragma unroll
                for (int r = 0; r < 4; ++r) {
                    const float cv = 1.0f / (1.0f + __expf(-cacc[r]));
                    out[3 * (p0 + q * 4 + r) + m] = (mk[r] > 0.5f) ? cv : 0.f;
                }
            }
            if (m == 0) {
                #pragma unroll
                for (int r = 0; r < 4; ++r)
                    out[3 * NPTS + p0 + q * 4 + r] = (mk[r] > 0.5f) ? __expf(hacc[r]) : 0.f;
            }
        }
    }
}

// ---------------- fallback: fused VALU kernel (if ws too small) -------------
__global__ __launch_bounds__(256) void ngp_fused(
    const float* __restrict__ x, const float* __restrict__ d,
    const float* __restrict__ tables,
    const float* __restrict__ w1a, const float* __restrict__ b1a,
    const float* __restrict__ w1b, const float* __restrict__ b1b,
    const float* __restrict__ w2a, const float* __restrict__ b2a,
    const float* __restrict__ w2b, const float* __restrict__ b2b,
    const float* __restrict__ w2c, const float* __restrict__ b2c,
    float* __restrict__ out)
{
    const int i = blockIdx.x * 256 + threadIdx.x;
    if (i >= NPTS) return;
    const float xs0 = x[3*i+0] / 3.0f;
    const float xs1 = x[3*i+1] / 3.0f;
    const float xs2 = x[3*i+2] / 3.0f;
    const bool mask = (fabsf(xs0) < 0.5f) & (fabsf(xs1) < 0.5f) & (fabsf(xs2) < 0.5f);
    const float xu0 = xs0 + 0.5f, xu1 = xs1 + 0.5f, xu2 = xs2 + 0.5f;

    float feats[32];
    #pragma unroll
    for (int l = 0; l < 16; ++l) {
        const float n = NLf[l];
        const float p0 = xu0 * n, p1 = xu1 * n, p2 = xu2 * n;
        const float f0 = floorf(p0), f1 = floorf(p1), f2 = floorf(p2);
        const float fr0 = p0 - f0, fr1 = p1 - f1, fr2 = p2 - f2;
        const int vf0 = (int)f0, vf1 = (int)f1, vf2 = (int)f2;
        const int vc0 = (int)ceilf(p0), vc1 = (int)ceilf(p1), vc2 = (int)ceilf(p2);
        const float2* tbl = (const float2*)(tables + (size_t)l * (TSZ * 2));
        float a0 = 0.f, a1 = 0.f;
        #pragma unroll
        for (int k = 0; k < 8; ++k) {
            const unsigned vx = (unsigned)(((CEILX >> k) & 1) ? vc0 : vf0);
            const unsigned vy = (unsigned)(((CEILY >> k) & 1) ? vc1 : vf1);
            const unsigned vz = (unsigned)(((CEILZ >> k) & 1) ? vc2 : vf2);
            const unsigned h = (vx ^ (vy * 2654435761u) ^ (vz * 805459861u)) & TMASK;
            const float wx = (k & 1)        ? fr0 : 1.0f - fr0;
            const float wy = ((k >> 1) & 1) ? fr1 : 1.0f - fr1;
            const float wz = ((k >> 2) & 1) ? fr2 : 1.0f - fr2;
            const float wgt = wx * wy * wz;
            const float2 t = tbl[h];
            a0 = fmaf(wgt, t.x, a0);
            a1 = fmaf(wgt, t.y, a1);
        }
        feats[2*l] = a0; feats[2*l+1] = a1;
    }

    float h2v[16];
    #pragma unroll
    for (int j = 0; j < 16; ++j) h2v[j] = b1b[j];
    #pragma unroll
    for (int c = 0; c < 4; ++c) {
        float h1c[16];
        #pragma unroll
        for (int jj = 0; jj < 16; ++jj) h1c[jj] = b1a[16*c + jj];
        #pragma unroll
        for (int i2 = 0; i2 < 32; ++i2) {
            const float f = feats[i2];
            #pragma unroll
            for (int jj = 0; jj < 16; ++jj)
                h1c[jj] = fmaf(f, w1a[i2*64 + 16*c + jj], h1c[jj]);
        }
        #pragma unroll
        for (int jj = 0; jj < 16; ++jj) {
            const float f = fmaxf(h1c[jj], 0.f);
            #pragma unroll
            for (int t = 0; t < 16; ++t)
                h2v[t] = fmaf(f, w1b[(16*c + jj)*16 + t], h2v[t]);
        }
    }

    float z1[64];
    #pragma unroll
    for (int j = 0; j < 64; ++j) z1[j] = b2a[j];
    #pragma unroll
    for (int i2 = 0; i2 < 16; ++i2) {
        const float f = h2v[i2];
        #pragma unroll
        for (int j = 0; j < 64; ++j) z1[j] = fmaf(f, w2a[i2*64 + j], z1[j]);
    }
    const float d0 = d[3*i+0], d1 = d[3*i+1], d2 = d[3*i+2];
    {
        const float* r = w2a + 16*64;
        #pragma unroll
        for (int j = 0; j < 64; ++j) z1[j] = fmaf(d0, r[j], z1[j]);
        r = w2a + 17*64;
        #pragma unroll
        for (int j = 0; j < 64; ++j) z1[j] = fmaf(d1, r[j], z1[j]);
        r = w2a + 18*64;
        #pragma unroll
        for (int j = 0; j < 64; ++j) z1[j] = fmaf(d2, r[j], z1[j]);
    }
    #pragma unroll
    for (int e = 0; e < 4; ++e) {
        const float mm = (float)(1 << e);
        const float dv[3] = {d0, d1, d2};
        #pragma unroll
        for (int a = 0; a < 3; ++a) {
            const float sv = __sinf(mm * dv[a]);
            const float* rs = w2a + (19 + 6*e + a)*64;
            #pragma unroll
            for (int j = 0; j < 64; ++j) z1[j] = fmaf(sv, rs[j], z1[j]);
        }
        #pragma unroll
        for (int a = 0; a < 3; ++a) {
            const float cv = __cosf(mm * dv[a]);
            const float* rc = w2a + (19 + 6*e + 3 + a)*64;
            #pragma unroll
            for (int j = 0; j < 64; ++j) z1[j] = fmaf(cv, rc[j], z1[j]);
        }
    }
    #pragma unroll
    for (int j = 0; j < 64; ++j) z1[j] = fmaxf(z1[j], 0.f);

    float ca = b2c[0], cb = b2c[1], cc = b2c[2];
    #pragma unroll
    for (int jc = 0; jc < 64; jc += 16) {
        float acc[16];
        #pragma unroll
        for (int jj = 0; jj < 16; ++jj) acc[jj] = b2b[jc + jj];
        #pragma unroll
        for (int i2 = 0; i2 < 64; ++i2) {
            const float f = z1[i2];
            #pragma unroll
            for (int jj = 0; jj < 16; ++jj)
                acc[jj] = fmaf(f, w2b[i2*64 + jc + jj], acc[jj]);
        }
        #pragma unroll
        for (int jj = 0; jj < 16; ++jj) {
            const float v = fmaxf(acc[jj], 0.f);
            ca = fmaf(v, w2c[(jc + jj)*3 + 0], ca);
            cb = fmaf(v, w2c[(jc + jj)*3 + 1], cb);
            cc = fmaf(v, w2c[(jc + jj)*3 + 2], cc);
        }
    }

    float r = 1.0f / (1.0f + __expf(-ca));
    float g = 1.0f / (1.0f + __expf(-cb));
    float b = 1.0f / (1.0f + __expf(-cc));
    float sigma;
    if (mask) { sigma = __expf(h2v[0]); }
    else { r = 0.f; g = 0.f; b = 0.f; sigma = 0.f; }
    out[3*i + 0] = r;
    out[3*i + 1] = g;
    out[3*i + 2] = b;
    out[3*NPTS + i] = sigma;
}

extern "C" void kernel_launch(void* const* d_in, const int* in_sizes, int n_in,
                              void* d_out, int out_size, void* d_ws, size_t ws_size,
                              hipStream_t stream) {
    const float* x      = (const float*)d_in[0];
    const float* d      = (const float*)d_in[1];
    const float* tables = (const float*)d_in[2];
    const float* w1a    = (const float*)d_in[3];
    const float* b1a    = (const float*)d_in[4];
    const float* w1b    = (const float*)d_in[5];
    const float* b1b    = (const float*)d_in[6];
    const float* w2a    = (const float*)d_in[7];
    const float* b2a    = (const float*)d_in[8];
    const float* w2b    = (const float*)d_in[9];
    const float* b2b    = (const float*)d_in[10];
    const float* w2c    = (const float*)d_in[11];
    const float* b2c    = (const float*)d_in[12];
    float* out = (float*)d_out;

    const size_t need = (size_t)NPTS * 16 * sizeof(float2);  // 64 MiB
    if (ws_size >= need) {
        float2* feats_ws = (float2*)d_ws;
        dim3 gh(HALF / 256, 16), bh(256);
        hipLaunchKernelGGL(ngp_hash2, gh, bh, 0, stream, x, tables, feats_ws);
        dim3 gm(NPTS / (256 * 16)), bm(256);   // 128 blocks? no: 524288/(4 waves*4 tiles*16)=2048
        gm = dim3(2048);
        hipLaunchKernelGGL(ngp_mlp_mfma, gm, bm, 0, stream,
                           x, d, feats_ws, w1a, b1a, w1b, b1b,
                           w2a, b2a, w2b, b2b, w2c, b2c, out);
    } else {
        dim3 grid(NPTS / 256), block(256);
        hipLaunchKernelGGL(ngp_fused, grid, block, 0, stream,
                           x, d, tables, w1a, b1a, w1b, b1b,
                           w2a, b2a, w2b, b2b, w2c, b2c, out);
    }
}

// Round 6
// 421.215 us; speedup vs baseline: 5.2076x; 1.0357x over previous
//
#include <hip/hip_runtime.h>
#include <math.h>

#define NPTS 524288
#define HALF (NPTS / 2)
#define TSZ  524288
#define TMASK (TSZ - 1)

typedef __attribute__((ext_vector_type(8))) short v8s;   // 8 x bf16 (4 VGPR)
typedef __attribute__((ext_vector_type(4))) float v4f;   // MFMA C/D frag

#define MFMA16(a, b, c) __builtin_amdgcn_mfma_f32_16x16x32_bf16(a, b, c, 0, 0, 0)

__device__ __constant__ float NLf[16] = {
    16.f, 22.f, 30.f, 42.f, 58.f, 80.f, 110.f, 152.f,
    209.f, 288.f, 397.f, 547.f, 754.f, 1039.f, 1432.f, 1974.f
};

#define CEILX 0xE2
#define CEILY 0xD4
#define CEILZ 0xB8

__device__ __forceinline__ short bf16r(float v) {  // f32 -> bf16 RNE
    unsigned b = __float_as_uint(v);
    b += 0x7FFFu + ((b >> 16) & 1u);
    return (short)(b >> 16);
}
__device__ __forceinline__ unsigned packbf(float a, float b) {
    return (unsigned)(unsigned short)bf16r(a) | ((unsigned)(unsigned short)bf16r(b) << 16);
}

// ---------------- kernel 0: pack fp32 tables -> bf16x2 (4 B/entry) ----------
// Halves the per-level L2 footprint (4 MB -> 2 MB): 2 levels co-resident per
// XCD L2 instead of 1 -> hash gather miss rate collapses (R5: FETCH=313 MB).
__global__ __launch_bounds__(256) void pack_tables(
    const float4* __restrict__ tbl, uint2* __restrict__ out)
{
    const int idx = blockIdx.x * 256 + threadIdx.x;   // handles 2 entries
    const float4 t = tbl[idx];
    out[idx] = make_uint2(packbf(t.x, t.y), packbf(t.z, t.w));
}

// ---------------- kernel 1: hash gather from packed tables ------------------
__global__ __launch_bounds__(256) void ngp_hash2b(
    const float* __restrict__ x, const unsigned* __restrict__ tables_pk,
    unsigned* __restrict__ feats_pk)
{
    const int i = blockIdx.x * 256 + threadIdx.x;    // [0, HALF)
    const int l = blockIdx.y;                        // level (slowest -> L2 locality)
    const float n = NLf[l];
    const unsigned* tbl = tables_pk + (size_t)l * TSZ;

    #pragma unroll
    for (int pp = 0; pp < 2; ++pp) {
        const int p = i + pp * HALF;
        const float xu0 = x[3*p+0] / 3.0f + 0.5f;
        const float xu1 = x[3*p+1] / 3.0f + 0.5f;
        const float xu2 = x[3*p+2] / 3.0f + 0.5f;
        const float p0 = xu0 * n, p1 = xu1 * n, p2 = xu2 * n;
        const float f0 = floorf(p0), f1 = floorf(p1), f2 = floorf(p2);
        const float fr0 = p0 - f0, fr1 = p1 - f1, fr2 = p2 - f2;
        const int vf0 = (int)f0, vf1 = (int)f1, vf2 = (int)f2;
        const int vc0 = (int)ceilf(p0), vc1 = (int)ceilf(p1), vc2 = (int)ceilf(p2);
        float a0 = 0.f, a1 = 0.f;
        #pragma unroll
        for (int k = 0; k < 8; ++k) {
            const unsigned vx = (unsigned)(((CEILX >> k) & 1) ? vc0 : vf0);
            const unsigned vy = (unsigned)(((CEILY >> k) & 1) ? vc1 : vf1);
            const unsigned vz = (unsigned)(((CEILZ >> k) & 1) ? vc2 : vf2);
            const unsigned h = (vx ^ (vy * 2654435761u) ^ (vz * 805459861u)) & TMASK;
            const float wx = (k & 1)        ? fr0 : 1.0f - fr0;
            const float wy = ((k >> 1) & 1) ? fr1 : 1.0f - fr1;
            const float wz = ((k >> 2) & 1) ? fr2 : 1.0f - fr2;
            const float wgt = wx * wy * wz;
            const unsigned tv = tbl[h];
            const float t0 = __uint_as_float(tv << 16);
            const float t1 = __uint_as_float(tv & 0xFFFF0000u);
            a0 = fmaf(wgt, t0, a0);
            a1 = fmaf(wgt, t1, a1);
        }
        feats_pk[(size_t)l * NPTS + p] = packbf(a0, a1);
    }
}

// ---------------- kernel 2: MFMA MLP, 2 concurrent tiles per wave -----------
// R5 post-mortem: 3300 cy/tile vs ~600 cy of work -> serial LDS chain, only
// 4 waves/SIMD to hide it. Here: 512-thr blocks (weights LDS amortized over
// 8 waves) and 2 independent tile-chains interleaved per wave -> 32
// concurrent chains/CU (2x R5).
// Layouts (m89/m120): A: row=lane&15, k=quad*8+j; B: col=lane&15, k=quad*8+j;
// C/D: col=lane&15, row=quad*4+reg.
#define PZ 72   // z-buffer pitch in shorts (144 B, 16B-aligned)

__global__ __launch_bounds__(512) void ngp_mlp_mfma2(
    const float* __restrict__ x, const float* __restrict__ d,
    const unsigned* __restrict__ feats_pk,
    const float* __restrict__ w1a, const float* __restrict__ b1a,
    const float* __restrict__ w1b, const float* __restrict__ b1b,
    const float* __restrict__ w2a, const float* __restrict__ b2a,
    const float* __restrict__ w2b, const float* __restrict__ b2b,
    const float* __restrict__ w2c, const float* __restrict__ b2c,
    float* __restrict__ out)
{
    __shared__ short sW1a[64 * 40];       // [n=64][k=32], pitch 40
    __shared__ short sW1b[16 * 72];       // [n=16][k=64], pitch 72
    __shared__ short sW2a[64 * 72];       // [n=64][k=64(43)], pitch 72
    __shared__ short sW2b[64 * 72];       // [n=64][k=64], pitch 72
    __shared__ short sW2c[16 * 72];       // [n=16(3)][k=64], pitch 72
    __shared__ short sZ[8 * 2 * 16 * PZ]; // 8 waves x 2 tile-buffers
    __shared__ float sMask[8 * 32];

    const int tid = threadIdx.x;

    // ---- stage weights (bf16, transposed [n][k]) ----
    for (int idx = tid; idx < 32 * 64; idx += 512) {
        const int k = idx >> 6, n2 = idx & 63;
        sW1a[n2 * 40 + k] = bf16r(w1a[k * 64 + n2]);
    }
    for (int idx = tid; idx < 64 * 16; idx += 512) {
        const int k = idx >> 4, n2 = idx & 15;
        sW1b[n2 * 72 + k] = bf16r(w1b[k * 16 + n2]);
    }
    for (int idx = tid; idx < 64 * 64; idx += 512) {
        const int k = idx >> 6, n2 = idx & 63;
        sW2a[n2 * 72 + k] = bf16r(k < 43 ? w2a[k * 64 + n2] : 0.f);
    }
    for (int idx = tid; idx < 64 * 64; idx += 512) {
        const int k = idx >> 6, n2 = idx & 63;
        sW2b[n2 * 72 + k] = bf16r(w2b[k * 64 + n2]);
    }
    for (int idx = tid; idx < 64 * 16; idx += 512) {
        const int k = idx >> 4, n2 = idx & 15;
        sW2c[n2 * 72 + k] = bf16r(n2 < 3 ? w2c[k * 3 + n2] : 0.f);
    }
    __syncthreads();

    const int wave = tid >> 6, lane = tid & 63;
    const int m = lane & 15, q = lane >> 4;
    short* zbs[2] = { &sZ[(wave * 2 + 0) * 16 * PZ], &sZ[(wave * 2 + 1) * 16 * PZ] };

    // hoisted per-lane biases
    float bb1a[4], bb2a[4], bb2b[4];
    #pragma unroll
    for (int ct = 0; ct < 4; ++ct) {
        bb1a[ct] = b1a[ct * 16 + m];
        bb2a[ct] = b2a[ct * 16 + m];
        bb2b[ct] = b2b[ct * 16 + m];
    }
    const float bb1b = b1b[m];
    const float bb2c = (m < 3) ? b2c[m] : 0.f;

    const int p0 = (blockIdx.x * 16 + wave * 2) * 16;   // wave covers [p0, p0+32)

    // ---- stage feats (packed bf16 pairs) + masks ----
    #pragma unroll
    for (int t2 = 0; t2 < 2; ++t2) {
        short* zb = zbs[t2];
        const int pb = p0 + t2 * 16;
        #pragma unroll
        for (int it = 0; it < 4; ++it) {
            const int l = it * 4 + q;
            *(unsigned*)(zb + m * PZ + 2 * l) = feats_pk[(size_t)l * NPTS + pb + m];
        }
    }
    if (lane < 32) {
        const int p = p0 + lane;
        const float xs0 = x[3*p+0] / 3.0f;
        const float xs1 = x[3*p+1] / 3.0f;
        const float xs2 = x[3*p+2] / 3.0f;
        sMask[wave * 32 + lane] =
            ((fabsf(xs0) < 0.5f) && (fabsf(xs1) < 0.5f) && (fabsf(xs2) < 0.5f)) ? 1.f : 0.f;
    }

    // ---- layer 1a: feats[16x32] @ w1a[32x64] -> relu ----
    #pragma unroll
    for (int t2 = 0; t2 < 2; ++t2) {
        short* zb = zbs[t2];
        const v8s a0 = *(const v8s*)(zb + m * PZ + q * 8);
        #pragma unroll
        for (int ct = 0; ct < 4; ++ct) {
            const float bv = bb1a[ct];
            v4f acc = {bv, bv, bv, bv};
            acc = MFMA16(a0, *(const v8s*)(sW1a + (ct * 16 + m) * 40 + q * 8), acc);
            #pragma unroll
            for (int r = 0; r < 4; ++r)
                zb[(q * 4 + r) * PZ + ct * 16 + m] = bf16r(fmaxf(acc[r], 0.f));
        }
    }

    // ---- layer 1b: h1[16x64] @ w1b[64x16] -> h (NO relu) ----
    v4f hacc[2];
    #pragma unroll
    for (int t2 = 0; t2 < 2; ++t2) {
        short* zb = zbs[t2];
        const v8s a10 = *(const v8s*)(zb + m * PZ + q * 8);
        const v8s a11 = *(const v8s*)(zb + m * PZ + 32 + q * 8);
        v4f hv = {bb1b, bb1b, bb1b, bb1b};
        hv = MFMA16(a10, *(const v8s*)(sW1b + m * 72 + q * 8), hv);
        hv = MFMA16(a11, *(const v8s*)(sW1b + m * 72 + 32 + q * 8), hv);
        hacc[t2] = hv;
        #pragma unroll
        for (int r = 0; r < 4; ++r)
            zb[(q * 4 + r) * PZ + m] = bf16r(hv[r]);
    }

    // ---- posenc fill: z[k=16..42], zeros k=43..63 ----
    #pragma unroll
    for (int t2 = 0; t2 < 2; ++t2) {
        short* zb = zbs[t2];
        const int p = p0 + t2 * 16 + m;
        const float dd0 = d[3*p+0], dd1 = d[3*p+1], dd2 = d[3*p+2];
        v8s pk;
        #pragma unroll
        for (int j = 0; j < 8; ++j) {
            const int k = 16 + q * 8 + j;
            float v;
            if (k < 19) {
                v = (k == 16) ? dd0 : ((k == 17) ? dd1 : dd2);
            } else if (k < 43) {
                const int idx = k - 19;
                const int e = idx / 6, w = idx - 6 * e;
                const float base = (w == 0 || w == 3) ? dd0 : ((w == 1 || w == 4) ? dd1 : dd2);
                const float s = (float)(1 << e) * base;
                v = (w < 3) ? __sinf(s) : __cosf(s);
            } else {
                v = 0.f;
            }
            pk[j] = bf16r(v);
        }
        *(v8s*)(zb + m * PZ + 16 + q * 8) = pk;
        *(unsigned long long*)(zb + m * PZ + 48 + q * 4) = 0ull;
    }

    // ---- layer 2a: z[16x64(43)] @ w2a -> relu ----
    #pragma unroll
    for (int t2 = 0; t2 < 2; ++t2) {
        short* zb = zbs[t2];
        const v8s a20 = *(const v8s*)(zb + m * PZ + q * 8);
        const v8s a21 = *(const v8s*)(zb + m * PZ + 32 + q * 8);
        #pragma unroll
        for (int ct = 0; ct < 4; ++ct) {
            const float bv = bb2a[ct];
            v4f acc = {bv, bv, bv, bv};
            acc = MFMA16(a20, *(const v8s*)(sW2a + (ct * 16 + m) * 72 + q * 8), acc);
            acc = MFMA16(a21, *(const v8s*)(sW2a + (ct * 16 + m) * 72 + 32 + q * 8), acc);
            #pragma unroll
            for (int r = 0; r < 4; ++r)
                zb[(q * 4 + r) * PZ + ct * 16 + m] = bf16r(fmaxf(acc[r], 0.f));
        }
    }

    // ---- layer 2b: z1[16x64] @ w2b -> relu ----
    #pragma unroll
    for (int t2 = 0; t2 < 2; ++t2) {
        short* zb = zbs[t2];
        const v8s a20 = *(const v8s*)(zb + m * PZ + q * 8);
        const v8s a21 = *(const v8s*)(zb + m * PZ + 32 + q * 8);
        #pragma unroll
        for (int ct = 0; ct < 4; ++ct) {
            const float bv = bb2b[ct];
            v4f acc = {bv, bv, bv, bv};
            acc = MFMA16(a20, *(const v8s*)(sW2b + (ct * 16 + m) * 72 + q * 8), acc);
            acc = MFMA16(a21, *(const v8s*)(sW2b + (ct * 16 + m) * 72 + 32 + q * 8), acc);
            #pragma unroll
            for (int r = 0; r < 4; ++r)
                zb[(q * 4 + r) * PZ + ct * 16 + m] = bf16r(fmaxf(acc[r], 0.f));
        }
    }

    // ---- layer 2c + epilogue ----
    #pragma unroll
    for (int t2 = 0; t2 < 2; ++t2) {
        short* zb = zbs[t2];
        const int pb = p0 + t2 * 16;
        const v8s a30 = *(const v8s*)(zb + m * PZ + q * 8);
        const v8s a31 = *(const v8s*)(zb + m * PZ + 32 + q * 8);
        v4f cacc = {bb2c, bb2c, bb2c, bb2c};
        cacc = MFMA16(a30, *(const v8s*)(sW2c + m * 72 + q * 8), cacc);
        cacc = MFMA16(a31, *(const v8s*)(sW2c + m * 72 + 32 + q * 8), cacc);

        float mk[4];
        #pragma unroll
        for (int r = 0; r < 4; ++r) mk[r] = sMask[wave * 32 + t2 * 16 + q * 4 + r];

        if (m < 3) {
            #pragma unroll
            for (int r = 0; r < 4; ++r) {
                const float cv = 1.0f / (1.0f + __expf(-cacc[r]));
                out[3 * (pb + q * 4 + r) + m] = (mk[r] > 0.5f) ? cv : 0.f;
            }
        }
        if (m == 0) {
            #pragma unroll
            for (int r = 0; r < 4; ++r)
                out[3 * NPTS + pb + q * 4 + r] = (mk[r] > 0.5f) ? __expf(hacc[t2][r]) : 0.f;
        }
    }
}

// ---------------- fallback: fused VALU kernel (if ws too small) -------------
__global__ __launch_bounds__(256) void ngp_fused(
    const float* __restrict__ x, const float* __restrict__ d,
    const float* __restrict__ tables,
    const float* __restrict__ w1a, const float* __restrict__ b1a,
    const float* __restrict__ w1b, const float* __restrict__ b1b,
    const float* __restrict__ w2a, const float* __restrict__ b2a,
    const float* __restrict__ w2b, const float* __restrict__ b2b,
    const float* __restrict__ w2c, const float* __restrict__ b2c,
    float* __restrict__ out)
{
    const int i = blockIdx.x * 256 + threadIdx.x;
    if (i >= NPTS) return;
    const float xs0 = x[3*i+0] / 3.0f;
    const float xs1 = x[3*i+1] / 3.0f;
    const float xs2 = x[3*i+2] / 3.0f;
    const bool mask = (fabsf(xs0) < 0.5f) & (fabsf(xs1) < 0.5f) & (fabsf(xs2) < 0.5f);
    const float xu0 = xs0 + 0.5f, xu1 = xs1 + 0.5f, xu2 = xs2 + 0.5f;

    float feats[32];
    #pragma unroll
    for (int l = 0; l < 16; ++l) {
        const float n = NLf[l];
        const float p0 = xu0 * n, p1 = xu1 * n, p2 = xu2 * n;
        const float f0 = floorf(p0), f1 = floorf(p1), f2 = floorf(p2);
        const float fr0 = p0 - f0, fr1 = p1 - f1, fr2 = p2 - f2;
        const int vf0 = (int)f0, vf1 = (int)f1, vf2 = (int)f2;
        const int vc0 = (int)ceilf(p0), vc1 = (int)ceilf(p1), vc2 = (int)ceilf(p2);
        const float2* tbl = (const float2*)(tables + (size_t)l * (TSZ * 2));
        float a0 = 0.f, a1 = 0.f;
        #pragma unroll
        for (int k = 0; k < 8; ++k) {
            const unsigned vx = (unsigned)(((CEILX >> k) & 1) ? vc0 : vf0);
            const unsigned vy = (unsigned)(((CEILY >> k) & 1) ? vc1 : vf1);
            const unsigned vz = (unsigned)(((CEILZ >> k) & 1) ? vc2 : vf2);
            const unsigned h = (vx ^ (vy * 2654435761u) ^ (vz * 805459861u)) & TMASK;
            const float wx = (k & 1)        ? fr0 : 1.0f - fr0;
            const float wy = ((k >> 1) & 1) ? fr1 : 1.0f - fr1;
            const float wz = ((k >> 2) & 1) ? fr2 : 1.0f - fr2;
            const float wgt = wx * wy * wz;
            const float2 t = tbl[h];
            a0 = fmaf(wgt, t.x, a0);
            a1 = fmaf(wgt, t.y, a1);
        }
        feats[2*l] = a0; feats[2*l+1] = a1;
    }

    float h2v[16];
    #pragma unroll
    for (int j = 0; j < 16; ++j) h2v[j] = b1b[j];
    #pragma unroll
    for (int c = 0; c < 4; ++c) {
        float h1c[16];
        #pragma unroll
        for (int jj = 0; jj < 16; ++jj) h1c[jj] = b1a[16*c + jj];
        #pragma unroll
        for (int i2 = 0; i2 < 32; ++i2) {
            const float f = feats[i2];
            #pragma unroll
            for (int jj = 0; jj < 16; ++jj)
                h1c[jj] = fmaf(f, w1a[i2*64 + 16*c + jj], h1c[jj]);
        }
        #pragma unroll
        for (int jj = 0; jj < 16; ++jj) {
            const float f = fmaxf(h1c[jj], 0.f);
            #pragma unroll
            for (int t = 0; t < 16; ++t)
                h2v[t] = fmaf(f, w1b[(16*c + jj)*16 + t], h2v[t]);
        }
    }

    float z1[64];
    #pragma unroll
    for (int j = 0; j < 64; ++j) z1[j] = b2a[j];
    #pragma unroll
    for (int i2 = 0; i2 < 16; ++i2) {
        const float f = h2v[i2];
        #pragma unroll
        for (int j = 0; j < 64; ++j) z1[j] = fmaf(f, w2a[i2*64 + j], z1[j]);
    }
    const float d0 = d[3*i+0], d1 = d[3*i+1], d2 = d[3*i+2];
    {
        const float* r = w2a + 16*64;
        #pragma unroll
        for (int j = 0; j < 64; ++j) z1[j] = fmaf(d0, r[j], z1[j]);
        r = w2a + 17*64;
        #pragma unroll
        for (int j = 0; j < 64; ++j) z1[j] = fmaf(d1, r[j], z1[j]);
        r = w2a + 18*64;
        #pragma unroll
        for (int j = 0; j < 64; ++j) z1[j] = fmaf(d2, r[j], z1[j]);
    }
    #pragma unroll
    for (int e = 0; e < 4; ++e) {
        const float mm = (float)(1 << e);
        const float dv[3] = {d0, d1, d2};
        #pragma unroll
        for (int a = 0; a < 3; ++a) {
            const float sv = __sinf(mm * dv[a]);
            const float* rs = w2a + (19 + 6*e + a)*64;
            #pragma unroll
            for (int j = 0; j < 64; ++j) z1[j] = fmaf(sv, rs[j], z1[j]);
        }
        #pragma unroll
        for (int a = 0; a < 3; ++a) {
            const float cv = __cosf(mm * dv[a]);
            const float* rc = w2a + (19 + 6*e + 3 + a)*64;
            #pragma unroll
            for (int j = 0; j < 64; ++j) z1[j] = fmaf(cv, rc[j], z1[j]);
        }
    }
    #pragma unroll
    for (int j = 0; j < 64; ++j) z1[j] = fmaxf(z1[j], 0.f);

    float ca = b2c[0], cb = b2c[1], cc = b2c[2];
    #pragma unroll
    for (int jc = 0; jc < 64; jc += 16) {
        float acc[16];
        #pragma unroll
        for (int jj = 0; jj < 16; ++jj) acc[jj] = b2b[jc + jj];
        #pragma unroll
        for (int i2 = 0; i2 < 64; ++i2) {
            const float f = z1[i2];
            #pragma unroll
            for (int jj = 0; jj < 16; ++jj)
                acc[jj] = fmaf(f, w2b[i2*64 + jc + jj], acc[jj]);
        }
        #pragma unroll
        for (int jj = 0; jj < 16; ++jj) {
            const float v = fmaxf(acc[jj], 0.f);
            ca = fmaf(v, w2c[(jc + jj)*3 + 0], ca);
            cb = fmaf(v, w2c[(jc + jj)*3 + 1], cb);
            cc = fmaf(v, w2c[(jc + jj)*3 + 2], cc);
        }
    }

    float r = 1.0f / (1.0f + __expf(-ca));
    float g = 1.0f / (1.0f + __expf(-cb));
    float b = 1.0f / (1.0f + __expf(-cc));
    float sigma;
    if (mask) { sigma = __expf(h2v[0]); }
    else { r = 0.f; g = 0.f; b = 0.f; sigma = 0.f; }
    out[3*i + 0] = r;
    out[3*i + 1] = g;
    out[3*i + 2] = b;
    out[3*NPTS + i] = sigma;
}

extern "C" void kernel_launch(void* const* d_in, const int* in_sizes, int n_in,
                              void* d_out, int out_size, void* d_ws, size_t ws_size,
                              hipStream_t stream) {
    const float* x      = (const float*)d_in[0];
    const float* d      = (const float*)d_in[1];
    const float* tables = (const float*)d_in[2];
    const float* w1a    = (const float*)d_in[3];
    const float* b1a    = (const float*)d_in[4];
    const float* w1b    = (const float*)d_in[5];
    const float* b1b    = (const float*)d_in[6];
    const float* w2a    = (const float*)d_in[7];
    const float* b2a    = (const float*)d_in[8];
    const float* w2b    = (const float*)d_in[9];
    const float* b2b    = (const float*)d_in[10];
    const float* w2c    = (const float*)d_in[11];
    const float* b2c    = (const float*)d_in[12];
    float* out = (float*)d_out;

    // ws layout: [0, 32 MiB) packed feats [L][N]; [32 MiB, 64 MiB) packed tables
    const size_t need = (size_t)16 * NPTS * 4 * 2;   // 64 MiB
    if (ws_size >= need) {
        unsigned* feats_pk  = (unsigned*)d_ws;
        unsigned* tables_pk = (unsigned*)d_ws + (size_t)16 * NPTS;

        dim3 gp(16 * TSZ / (256 * 2)), bp(256);
        hipLaunchKernelGGL(pack_tables, gp, bp, 0, stream,
                           (const float4*)tables, (uint2*)tables_pk);

        dim3 gh(HALF / 256, 16), bh(256);
        hipLaunchKernelGGL(ngp_hash2b, gh, bh, 0, stream, x, tables_pk, feats_pk);

        dim3 gm(2048), bm(512);
        hipLaunchKernelGGL(ngp_mlp_mfma2, gm, bm, 0, stream,
                           x, d, feats_pk, w1a, b1a, w1b, b1b,
                           w2a, b2a, w2b, b2b, w2c, b2c, out);
    } else {
        dim3 grid(NPTS / 256), block(256);
        hipLaunchKernelGGL(ngp_fused, grid, block, 0, stream,
                           x, d, tables, w1a, b1a, w1b, b1b,
                           w2a, b2a, w2b, b2b, w2c, b2c, out);
    }
}